// Round 1
// baseline (863.619 us; speedup 1.0000x reference)
//
#include <hip/hip_runtime.h>
#include <cfloat>

constexpr int BATCH = 8, NPTS = 2048, KNN = 8;
constexpr int M = BATCH * NPTS;   // 16384 nodes
constexpr int CTXW = 515;

__device__ __forceinline__ float lrelu(float v) { return v > 0.0f ? v : 0.2f * v; }

// ---------------- ctx vector ----------------
__global__ void build_ctx(const float* __restrict__ beta, const float* __restrict__ ctxv,
                          const float* __restrict__ cond, float* __restrict__ ctx) {
    int b = blockIdx.x;
    float be = beta[b];
    for (int i = threadIdx.x; i < CTXW; i += blockDim.x) {
        float v;
        if (i == 0) v = be;
        else if (i == 1) v = sinf(be);
        else if (i == 2) v = cosf(be);
        else if (i < 259) v = ctxv[b * 256 + (i - 3)];
        else v = cond[b * 256 + (i - 259)];
        ctx[b * CTXW + i] = v;
    }
}

// bias_ctx[b][f] = bvec[f] + sum_c ctx[b][c] * W[rowOff + c][f]
__global__ void ctx_bias(const float* __restrict__ ctx, const float* __restrict__ W,
                         const float* __restrict__ bvec, float* __restrict__ out,
                         int rowOff, int F) {
    int gid = blockIdx.x * blockDim.x + threadIdx.x;
    if (gid >= BATCH * F) return;
    int b = gid / F, f = gid - b * F;
    const float* w = W + (size_t)rowOff * F + f;
    const float* c = ctx + b * CTXW;
    float s = bvec[f];
    for (int i = 0; i < CTXW; ++i) s = fmaf(c[i], w[(size_t)i * F], s);
    out[(size_t)b * F + f] = s;
}

// pack Wcat (D x 2F): [W[0:D,:] | W[D:2D,:]]
__global__ void pack_w(const float* __restrict__ W, float* __restrict__ Wp, int D, int F) {
    int gid = blockIdx.x * blockDim.x + threadIdx.x;
    int F2 = 2 * F;
    if (gid >= D * F2) return;
    int k = gid / F2, f = gid - k * F2;
    Wp[gid] = (f < F) ? W[(size_t)k * F + f] : W[(size_t)(D + k) * F + (f - F)];
}

// ---------------- kNN (fp64 distances to match np fp64 reference ordering) ----------------
__global__ __launch_bounds__(256) void knn_kernel(const float* __restrict__ x, int* __restrict__ idx) {
    __shared__ float xs[NPTS][3];
    __shared__ double sqs[NPTS];
    int b = blockIdx.y;
    const float* xb = x + (size_t)b * NPTS * 3;
    for (int i = threadIdx.x; i < NPTS; i += 256) {
        float a0 = xb[i * 3], a1 = xb[i * 3 + 1], a2 = xb[i * 3 + 2];
        xs[i][0] = a0; xs[i][1] = a1; xs[i][2] = a2;
        sqs[i] = ((double)a0 * a0 + (double)a1 * a1) + (double)a2 * a2;
    }
    __syncthreads();
    int n = blockIdx.x * 256 + threadIdx.x;
    float n0 = xs[n][0], n1 = xs[n][1], n2 = xs[n][2];
    double sqn = sqs[n];
    double best[8];
    int bi[8];
#pragma unroll
    for (int k = 0; k < 8; ++k) { best[k] = DBL_MAX; bi[k] = 0; }
    for (int m = 0; m < NPTS; ++m) {
        if (m == n) continue;
        double dot = ((double)n0 * xs[m][0] + (double)n1 * xs[m][1]) + (double)n2 * xs[m][2];
        double d = (sqn + sqs[m]) - 2.0 * dot;
        if (d < best[7]) {
            double cd = d; int ci = m;
#pragma unroll
            for (int j = 0; j < 8; ++j) {
                if (cd < best[j]) {
                    double td = best[j]; best[j] = cd; cd = td;
                    int ti = bi[j]; bi[j] = ci; ci = ti;
                }
            }
        }
    }
    int gn = b * NPTS + n;
#pragma unroll
    for (int k = 0; k < 8; ++k) idx[(size_t)gn * 8 + k] = b * NPTS + bi[k];
}

// ---------------- init MLP + LayerNorm (one wave per node, lane = channel) ----------------
__global__ __launch_bounds__(256) void init_ln(const float* __restrict__ x, const float* __restrict__ W0,
                                               const float* __restrict__ b0, const float* __restrict__ g,
                                               const float* __restrict__ be, float* __restrict__ feat) {
    int t = blockIdx.x * 256 + threadIdx.x;
    int node = t >> 6, c = t & 63;
    const float* xp = x + (size_t)node * 3;
    float h = fmaf(xp[0], W0[c], fmaf(xp[1], W0[64 + c], fmaf(xp[2], W0[128 + c], b0[c])));
    h = lrelu(h);
    float s = h;
#pragma unroll
    for (int o = 32; o > 0; o >>= 1) s += __shfl_xor(s, o);
    float mu = s * (1.0f / 64.0f);
    float tt = h - mu;
    float q = tt * tt;
#pragma unroll
    for (int o = 32; o > 0; o >>= 1) q += __shfl_xor(q, o);
    float var = q * (1.0f / 64.0f);
    feat[t] = tt * rsqrtf(var + 1e-5f) * g[c] + be[c];
}

// ---------------- fp32 tiled GEMM: C(MxN) = A(MxK) @ B(KxN), BM=128 BN=64 BK=32 ----------------
__global__ __launch_bounds__(256) void gemm128x64(const float* __restrict__ A, const float* __restrict__ B,
                                                  float* __restrict__ C, int N, int K,
                                                  const float* __restrict__ bias, int fuse_lrelu) {
    __shared__ float As[32][129];  // [k][m], stride 129 -> conflict-free scalar access
    __shared__ float Bs[32][64];
    int tid = threadIdx.x;
    int mBase = blockIdx.x * 128;
    int nBase = blockIdx.y * 64;
    int tx = tid & 15, ty = tid >> 4;
    int ar = tid >> 3, ac = (tid & 7) * 4;
    int bk = tid >> 4, bn = (tid & 15) * 4;
    float acc[8][4];
#pragma unroll
    for (int i = 0; i < 8; ++i)
#pragma unroll
        for (int j = 0; j < 4; ++j) acc[i][j] = 0.0f;

    for (int k0 = 0; k0 < K; k0 += 32) {
        float4 a0 = *(const float4*)(A + (size_t)(mBase + ar) * K + k0 + ac);
        float4 a1 = *(const float4*)(A + (size_t)(mBase + ar + 32) * K + k0 + ac);
        float4 a2 = *(const float4*)(A + (size_t)(mBase + ar + 64) * K + k0 + ac);
        float4 a3 = *(const float4*)(A + (size_t)(mBase + ar + 96) * K + k0 + ac);
        float4 b0 = *(const float4*)(B + (size_t)(k0 + bk) * N + nBase + bn);
        float4 b1 = *(const float4*)(B + (size_t)(k0 + bk + 16) * N + nBase + bn);
        __syncthreads();
        As[ac + 0][ar] = a0.x; As[ac + 1][ar] = a0.y; As[ac + 2][ar] = a0.z; As[ac + 3][ar] = a0.w;
        As[ac + 0][ar + 32] = a1.x; As[ac + 1][ar + 32] = a1.y; As[ac + 2][ar + 32] = a1.z; As[ac + 3][ar + 32] = a1.w;
        As[ac + 0][ar + 64] = a2.x; As[ac + 1][ar + 64] = a2.y; As[ac + 2][ar + 64] = a2.z; As[ac + 3][ar + 64] = a2.w;
        As[ac + 0][ar + 96] = a3.x; As[ac + 1][ar + 96] = a3.y; As[ac + 2][ar + 96] = a3.z; As[ac + 3][ar + 96] = a3.w;
        *(float4*)&Bs[bk][bn] = b0;
        *(float4*)&Bs[bk + 16][bn] = b1;
        __syncthreads();
#pragma unroll
        for (int kk = 0; kk < 32; ++kk) {
            float av[8], bv[4];
#pragma unroll
            for (int i = 0; i < 8; ++i) av[i] = As[kk][ty * 8 + i];
            float4 bq = *(const float4*)&Bs[kk][tx * 4];
            bv[0] = bq.x; bv[1] = bq.y; bv[2] = bq.z; bv[3] = bq.w;
#pragma unroll
            for (int i = 0; i < 8; ++i)
#pragma unroll
                for (int j = 0; j < 4; ++j) acc[i][j] = fmaf(av[i], bv[j], acc[i][j]);
        }
    }
    float bb[4] = {0.f, 0.f, 0.f, 0.f};
    if (bias) {
#pragma unroll
        for (int j = 0; j < 4; ++j) bb[j] = bias[nBase + tx * 4 + j];
    }
#pragma unroll
    for (int i = 0; i < 8; ++i) {
        int m = mBase + ty * 8 + i;
        float4 r;
        r.x = acc[i][0] + bb[0]; r.y = acc[i][1] + bb[1];
        r.z = acc[i][2] + bb[2]; r.w = acc[i][3] + bb[3];
        if (fuse_lrelu) { r.x = lrelu(r.x); r.y = lrelu(r.y); r.z = lrelu(r.z); r.w = lrelu(r.w); }
        *(float4*)(C + (size_t)m * N + nBase + tx * 4) = r;
    }
}

// ---------------- edge aggregate: out[n] = lrelu(U[n] - V[n] + bias[b] + max_k V[idx_k]) ----------------
__global__ __launch_bounds__(256) void edge_max(const float* __restrict__ UV, const int* __restrict__ idx,
                                                const float* __restrict__ bias, float* __restrict__ out,
                                                int F, int lf /* log2(F/4) */) {
    int gid = blockIdx.x * 256 + threadIdx.x;
    int fq = F >> 2;
    int n = gid >> lf;
    int f = (gid & (fq - 1)) << 2;
    int b = n >> 11;
    int F2 = F << 1;
    const float* base = UV + (size_t)n * F2;
    float4 u = *(const float4*)(base + f);
    float4 v = *(const float4*)(base + F + f);
    const int* ip = idx + (size_t)n * 8;
    float4 mx = make_float4(-FLT_MAX, -FLT_MAX, -FLT_MAX, -FLT_MAX);
#pragma unroll
    for (int k = 0; k < 8; ++k) {
        const float4 w = *(const float4*)(UV + (size_t)ip[k] * F2 + F + f);
        mx.x = fmaxf(mx.x, w.x); mx.y = fmaxf(mx.y, w.y);
        mx.z = fmaxf(mx.z, w.z); mx.w = fmaxf(mx.w, w.w);
    }
    const float4 bb = *(const float4*)(bias + (size_t)b * F + f);
    float4 z;
    z.x = lrelu(u.x - v.x + bb.x + mx.x);
    z.y = lrelu(u.y - v.y + bb.y + mx.y);
    z.z = lrelu(u.z - v.z + bb.z + mx.z);
    z.w = lrelu(u.w - v.w + bb.w + mx.w);
    *(float4*)(out + (size_t)n * F + f) = z;
}

// ---------------- final: out = x + hf @ Wf2 + bf2 ----------------
__global__ __launch_bounds__(256) void final_out(const float* __restrict__ hf, const float* __restrict__ Wf2,
                                                 const float* __restrict__ bf2, const float* __restrict__ x,
                                                 float* __restrict__ out) {
    int n = blockIdx.x * 256 + threadIdx.x;  // 16384 nodes
    const float* h = hf + (size_t)n * 256;
    float s0 = bf2[0], s1 = bf2[1], s2 = bf2[2];
    for (int k4 = 0; k4 < 64; ++k4) {
        float4 hv = *(const float4*)(h + k4 * 4);
        const float* w = Wf2 + k4 * 12;
        s0 = fmaf(hv.x, w[0], s0); s1 = fmaf(hv.x, w[1], s1); s2 = fmaf(hv.x, w[2], s2);
        s0 = fmaf(hv.y, w[3], s0); s1 = fmaf(hv.y, w[4], s1); s2 = fmaf(hv.y, w[5], s2);
        s0 = fmaf(hv.z, w[6], s0); s1 = fmaf(hv.z, w[7], s1); s2 = fmaf(hv.z, w[8], s2);
        s0 = fmaf(hv.w, w[9], s0); s1 = fmaf(hv.w, w[10], s1); s2 = fmaf(hv.w, w[11], s2);
    }
    out[n * 3 + 0] = x[n * 3 + 0] + s0;
    out[n * 3 + 1] = x[n * 3 + 1] + s1;
    out[n * 3 + 2] = x[n * 3 + 2] + s2;
}

extern "C" void kernel_launch(void* const* d_in, const int* in_sizes, int n_in,
                              void* d_out, int out_size, void* d_ws, size_t ws_size,
                              hipStream_t stream) {
    const float* x    = (const float*)d_in[0];
    const float* beta = (const float*)d_in[1];
    const float* ctxv = (const float*)d_in[2];
    const float* cond = (const float*)d_in[3];
    const float* W0   = (const float*)d_in[4];
    const float* b0   = (const float*)d_in[5];
    const float* ln_g = (const float*)d_in[6];
    const float* ln_b = (const float*)d_in[7];
    const float* W1   = (const float*)d_in[8];
    const float* b1   = (const float*)d_in[9];
    const float* W2   = (const float*)d_in[10];
    const float* b2   = (const float*)d_in[11];
    const float* W3   = (const float*)d_in[12];
    const float* b3   = (const float*)d_in[13];
    const float* Wf1  = (const float*)d_in[14];
    const float* bf1  = (const float*)d_in[15];
    const float* Wf2  = (const float*)d_in[16];
    const float* bf2  = (const float*)d_in[17];
    float* out = (float*)d_out;

    char* ws = (char*)d_ws;
    size_t off = 0;
    auto alloc = [&](size_t bytes) -> void* {
        void* p = ws + off;
        off += bytes;
        off = (off + 511) & ~(size_t)511;
        return p;
    };

    int*   idx   = (int*)alloc((size_t)M * 8 * 4);
    float* ctx   = (float*)alloc((size_t)BATCH * CTXW * 4);
    float* bias1 = (float*)alloc((size_t)BATCH * 128 * 4);
    float* bias2 = (float*)alloc((size_t)BATCH * 256 * 4);
    float* bias3 = (float*)alloc((size_t)BATCH * 512 * 4);
    float* W1p   = (float*)alloc((size_t)64 * 256 * 4);
    float* W2p   = (float*)alloc((size_t)128 * 512 * 4);
    float* W3p   = (float*)alloc((size_t)256 * 1024 * 4);
    float* R1    = (float*)alloc((size_t)M * 1024 * 4);  // feat0, later UV3
    float* R2    = (float*)alloc((size_t)M * 512 * 4);   // UV1, UV2, x3
    float* R3    = (float*)alloc((size_t)M * 256 * 4);   // x1, hf
    float* R4    = (float*)alloc((size_t)M * 256 * 4);   // x2

    float* feat0 = R1;
    float* UV1 = R2;  float* x1 = R3;
    float* UV2 = R2;  float* x2 = R4;
    float* UV3 = R1;  float* x3 = R2;
    float* hf  = R3;

    build_ctx<<<BATCH, 256, 0, stream>>>(beta, ctxv, cond, ctx);
    ctx_bias<<<(BATCH * 128 + 255) / 256, 256, 0, stream>>>(ctx, W1, b1, bias1, 128, 128);
    ctx_bias<<<(BATCH * 256 + 255) / 256, 256, 0, stream>>>(ctx, W2, b2, bias2, 256, 256);
    ctx_bias<<<(BATCH * 512 + 255) / 256, 256, 0, stream>>>(ctx, W3, b3, bias3, 512, 512);
    pack_w<<<(64 * 256 + 255) / 256, 256, 0, stream>>>(W1, W1p, 64, 128);
    pack_w<<<(128 * 512 + 255) / 256, 256, 0, stream>>>(W2, W2p, 128, 256);
    pack_w<<<(256 * 1024 + 255) / 256, 256, 0, stream>>>(W3, W3p, 256, 512);

    knn_kernel<<<dim3(NPTS / 256, BATCH), 256, 0, stream>>>(x, idx);
    init_ln<<<M * 64 / 256, 256, 0, stream>>>(x, W0, b0, ln_g, ln_b, feat0);

    gemm128x64<<<dim3(M / 128, 256 / 64), 256, 0, stream>>>(feat0, W1p, UV1, 256, 64, nullptr, 0);
    edge_max<<<M * (128 / 4) / 256, 256, 0, stream>>>(UV1, idx, bias1, x1, 128, 5);

    gemm128x64<<<dim3(M / 128, 512 / 64), 256, 0, stream>>>(x1, W2p, UV2, 512, 128, nullptr, 0);
    edge_max<<<M * (256 / 4) / 256, 256, 0, stream>>>(UV2, idx, bias2, x2, 256, 6);

    gemm128x64<<<dim3(M / 128, 1024 / 64), 256, 0, stream>>>(x2, W3p, UV3, 1024, 256, nullptr, 0);
    edge_max<<<M * (512 / 4) / 256, 256, 0, stream>>>(UV3, idx, bias3, x3, 512, 7);

    gemm128x64<<<dim3(M / 128, 256 / 64), 256, 0, stream>>>(x3, Wf1, hf, 256, 512, bf1, 1);

    final_out<<<M / 256, 256, 0, stream>>>(hf, Wf2, bf2, x, out);
}

// Round 2
// 530.572 us; speedup vs baseline: 1.6277x; 1.6277x over previous
//
#include <hip/hip_runtime.h>
#include <cfloat>

constexpr int BATCH = 8, NPTS = 2048, KNN = 8;
constexpr int M = BATCH * NPTS;   // 16384 nodes
constexpr int CTXW = 515;

__device__ __forceinline__ float lrelu(float v) { return v > 0.0f ? v : 0.2f * v; }

// ---------------- ctx vector ----------------
__global__ void build_ctx(const float* __restrict__ beta, const float* __restrict__ ctxv,
                          const float* __restrict__ cond, float* __restrict__ ctx) {
    int b = blockIdx.x;
    float be = beta[b];
    for (int i = threadIdx.x; i < CTXW; i += blockDim.x) {
        float v;
        if (i == 0) v = be;
        else if (i == 1) v = sinf(be);
        else if (i == 2) v = cosf(be);
        else if (i < 259) v = ctxv[b * 256 + (i - 3)];
        else v = cond[b * 256 + (i - 259)];
        ctx[b * CTXW + i] = v;
    }
}

// bias_ctx[b][f] = bvec[f] + sum_c ctx[b][c] * W[rowOff + c][f]
__global__ void ctx_bias(const float* __restrict__ ctx, const float* __restrict__ W,
                         const float* __restrict__ bvec, float* __restrict__ out,
                         int rowOff, int F) {
    int gid = blockIdx.x * blockDim.x + threadIdx.x;
    if (gid >= BATCH * F) return;
    int b = gid / F, f = gid - b * F;
    const float* w = W + (size_t)rowOff * F + f;
    const float* c = ctx + b * CTXW;
    float s = bvec[f];
    for (int i = 0; i < CTXW; ++i) s = fmaf(c[i], w[(size_t)i * F], s);
    out[(size_t)b * F + f] = s;
}

// pack Wcat (D x 2F): [W[0:D,:] | W[D:2D,:]]
__global__ void pack_w(const float* __restrict__ W, float* __restrict__ Wp, int D, int F) {
    int gid = blockIdx.x * blockDim.x + threadIdx.x;
    int F2 = 2 * F;
    if (gid >= D * F2) return;
    int k = gid / F2, f = gid - k * F2;
    Wp[gid] = (f < F) ? W[(size_t)k * F + f] : W[(size_t)(D + k) * F + (f - F)];
}

// ---------------- kNN: candidate-split, fp64 distances (bit-identical to np ref) ----------------
// Block: 32 nodes x 8 candidate-chunks = 256 threads. Each thread scans 256 candidates,
// keeps sorted top-8 in registers; LDS merge (stable, chunk/index order) per node.
__global__ __launch_bounds__(256) void knn_kernel(const float* __restrict__ x, int* __restrict__ idx) {
    __shared__ __align__(16) char pool[40960];
    float (*xs)[3] = (float(*)[3])pool;           // 2048*12 = 24576 B
    double* sqs = (double*)(pool + 24576);        // 2048*8  = 16384 B
    int b = blockIdx.y;
    const float* xb = x + (size_t)b * NPTS * 3;
    int tid = threadIdx.x;
    for (int i = tid; i < NPTS; i += 256) {
        float a0 = xb[i * 3], a1 = xb[i * 3 + 1], a2 = xb[i * 3 + 2];
        xs[i][0] = a0; xs[i][1] = a1; xs[i][2] = a2;
        sqs[i] = ((double)a0 * a0 + (double)a1 * a1) + (double)a2 * a2;
    }
    __syncthreads();

    int nl = tid & 31;            // node within block
    int chunk = tid >> 5;         // candidate chunk 0..7 (uniform per half-wave)
    int n = blockIdx.x * 32 + nl; // node within batch
    float n0 = xs[n][0], n1 = xs[n][1], n2 = xs[n][2];
    double sqn = sqs[n];
    double best[8];
    int bi[8];
#pragma unroll
    for (int k = 0; k < 8; ++k) { best[k] = DBL_MAX; bi[k] = 0; }
    int mbase = chunk * 256;
    for (int i = 0; i < 256; ++i) {
        int m = mbase + i;
        double dot = ((double)n0 * xs[m][0] + (double)n1 * xs[m][1]) + (double)n2 * xs[m][2];
        double d = (sqn + sqs[m]) - 2.0 * dot;
        if (m != n && d < best[7]) {
            double cd = d; int ci = m;
#pragma unroll
            for (int j = 0; j < 8; ++j) {
                if (cd < best[j]) {
                    double td = best[j]; best[j] = cd; cd = td;
                    int ti = bi[j]; bi[j] = ci; ci = ti;
                }
            }
        }
    }
    __syncthreads();
    // overlay merge buffers on the point tile (chunk-major: conflict-free)
    double* pd = (double*)pool;          // [64][32] = 16384 B
    int*    pi = (int*)(pool + 16384);   // [64][32] =  8192 B
#pragma unroll
    for (int k = 0; k < 8; ++k) {
        pd[(chunk * 8 + k) * 32 + nl] = best[k];
        pi[(chunk * 8 + k) * 32 + nl] = bi[k];
    }
    __syncthreads();
    if (tid < 32) {
        int node = tid;
        double fb[8]; int fi[8];
#pragma unroll
        for (int k = 0; k < 8; ++k) { fb[k] = DBL_MAX; fi[k] = 0; }
        for (int c = 0; c < 8; ++c) {
            for (int k = 0; k < 8; ++k) {
                double d = pd[(c * 8 + k) * 32 + node];
                if (d >= fb[7]) break;  // chunk lists are ascending
                int ci = pi[(c * 8 + k) * 32 + node];
                double cd = d;
#pragma unroll
                for (int j = 0; j < 8; ++j) {
                    if (cd < fb[j]) {
                        double td = fb[j]; fb[j] = cd; cd = td;
                        int ti = fi[j]; fi[j] = ci; ci = ti;
                    }
                }
            }
        }
        int gn = b * NPTS + blockIdx.x * 32 + node;
#pragma unroll
        for (int k = 0; k < 8; ++k) idx[(size_t)gn * 8 + k] = b * NPTS + fi[k];
    }
}

// ---------------- init MLP + LayerNorm (one wave per node, lane = channel) ----------------
__global__ __launch_bounds__(256) void init_ln(const float* __restrict__ x, const float* __restrict__ W0,
                                               const float* __restrict__ b0, const float* __restrict__ g,
                                               const float* __restrict__ be, float* __restrict__ feat) {
    int t = blockIdx.x * 256 + threadIdx.x;
    int node = t >> 6, c = t & 63;
    const float* xp = x + (size_t)node * 3;
    float h = fmaf(xp[0], W0[c], fmaf(xp[1], W0[64 + c], fmaf(xp[2], W0[128 + c], b0[c])));
    h = lrelu(h);
    float s = h;
#pragma unroll
    for (int o = 32; o > 0; o >>= 1) s += __shfl_xor(s, o);
    float mu = s * (1.0f / 64.0f);
    float tt = h - mu;
    float q = tt * tt;
#pragma unroll
    for (int o = 32; o > 0; o >>= 1) q += __shfl_xor(q, o);
    float var = q * (1.0f / 64.0f);
    feat[t] = tt * rsqrtf(var + 1e-5f) * g[c] + be[c];
}

// ---------------- fp32 tiled GEMM: C(MxN) = A(MxK) @ B(KxN), BM=128 BN=64 BK=32 ----------------
__global__ __launch_bounds__(256) void gemm128x64(const float* __restrict__ A, const float* __restrict__ B,
                                                  float* __restrict__ C, int N, int K,
                                                  const float* __restrict__ bias, int fuse_lrelu) {
    __shared__ float As[32][129];  // [k][m], stride 129 -> conflict-free scalar access
    __shared__ float Bs[32][64];
    int tid = threadIdx.x;
    int mBase = blockIdx.x * 128;
    int nBase = blockIdx.y * 64;
    int tx = tid & 15, ty = tid >> 4;
    int ar = tid >> 3, ac = (tid & 7) * 4;
    int bk = tid >> 4, bn = (tid & 15) * 4;
    float acc[8][4];
#pragma unroll
    for (int i = 0; i < 8; ++i)
#pragma unroll
        for (int j = 0; j < 4; ++j) acc[i][j] = 0.0f;

    for (int k0 = 0; k0 < K; k0 += 32) {
        float4 a0 = *(const float4*)(A + (size_t)(mBase + ar) * K + k0 + ac);
        float4 a1 = *(const float4*)(A + (size_t)(mBase + ar + 32) * K + k0 + ac);
        float4 a2 = *(const float4*)(A + (size_t)(mBase + ar + 64) * K + k0 + ac);
        float4 a3 = *(const float4*)(A + (size_t)(mBase + ar + 96) * K + k0 + ac);
        float4 b0 = *(const float4*)(B + (size_t)(k0 + bk) * N + nBase + bn);
        float4 b1 = *(const float4*)(B + (size_t)(k0 + bk + 16) * N + nBase + bn);
        __syncthreads();
        As[ac + 0][ar] = a0.x; As[ac + 1][ar] = a0.y; As[ac + 2][ar] = a0.z; As[ac + 3][ar] = a0.w;
        As[ac + 0][ar + 32] = a1.x; As[ac + 1][ar + 32] = a1.y; As[ac + 2][ar + 32] = a1.z; As[ac + 3][ar + 32] = a1.w;
        As[ac + 0][ar + 64] = a2.x; As[ac + 1][ar + 64] = a2.y; As[ac + 2][ar + 64] = a2.z; As[ac + 3][ar + 64] = a2.w;
        As[ac + 0][ar + 96] = a3.x; As[ac + 1][ar + 96] = a3.y; As[ac + 2][ar + 96] = a3.z; As[ac + 3][ar + 96] = a3.w;
        *(float4*)&Bs[bk][bn] = b0;
        *(float4*)&Bs[bk + 16][bn] = b1;
        __syncthreads();
#pragma unroll
        for (int kk = 0; kk < 32; ++kk) {
            float av[8], bv[4];
#pragma unroll
            for (int i = 0; i < 8; ++i) av[i] = As[kk][ty * 8 + i];
            float4 bq = *(const float4*)&Bs[kk][tx * 4];
            bv[0] = bq.x; bv[1] = bq.y; bv[2] = bq.z; bv[3] = bq.w;
#pragma unroll
            for (int i = 0; i < 8; ++i)
#pragma unroll
                for (int j = 0; j < 4; ++j) acc[i][j] = fmaf(av[i], bv[j], acc[i][j]);
        }
    }
    float bb[4] = {0.f, 0.f, 0.f, 0.f};
    if (bias) {
#pragma unroll
        for (int j = 0; j < 4; ++j) bb[j] = bias[nBase + tx * 4 + j];
    }
#pragma unroll
    for (int i = 0; i < 8; ++i) {
        int m = mBase + ty * 8 + i;
        float4 r;
        r.x = acc[i][0] + bb[0]; r.y = acc[i][1] + bb[1];
        r.z = acc[i][2] + bb[2]; r.w = acc[i][3] + bb[3];
        if (fuse_lrelu) { r.x = lrelu(r.x); r.y = lrelu(r.y); r.z = lrelu(r.z); r.w = lrelu(r.w); }
        *(float4*)(C + (size_t)m * N + nBase + tx * 4) = r;
    }
}

// ---------------- edge aggregate: out[n] = lrelu(U[n] - V[n] + bias[b] + max_k V[idx_k]) ----------------
__global__ __launch_bounds__(256) void edge_max(const float* __restrict__ UV, const int* __restrict__ idx,
                                                const float* __restrict__ bias, float* __restrict__ out,
                                                int F, int lf /* log2(F/4) */) {
    int gid = blockIdx.x * 256 + threadIdx.x;
    int fq = F >> 2;
    int n = gid >> lf;
    int f = (gid & (fq - 1)) << 2;
    int b = n >> 11;
    int F2 = F << 1;
    const float* base = UV + (size_t)n * F2;
    float4 u = *(const float4*)(base + f);
    float4 v = *(const float4*)(base + F + f);
    const int* ip = idx + (size_t)n * 8;
    float4 mx = make_float4(-FLT_MAX, -FLT_MAX, -FLT_MAX, -FLT_MAX);
#pragma unroll
    for (int k = 0; k < 8; ++k) {
        const float4 w = *(const float4*)(UV + (size_t)ip[k] * F2 + F + f);
        mx.x = fmaxf(mx.x, w.x); mx.y = fmaxf(mx.y, w.y);
        mx.z = fmaxf(mx.z, w.z); mx.w = fmaxf(mx.w, w.w);
    }
    const float4 bb = *(const float4*)(bias + (size_t)b * F + f);
    float4 z;
    z.x = lrelu(u.x - v.x + bb.x + mx.x);
    z.y = lrelu(u.y - v.y + bb.y + mx.y);
    z.z = lrelu(u.z - v.z + bb.z + mx.z);
    z.w = lrelu(u.w - v.w + bb.w + mx.w);
    *(float4*)(out + (size_t)n * F + f) = z;
}

// ---------------- final: out = x + hf @ Wf2 + bf2 ----------------
__global__ __launch_bounds__(256) void final_out(const float* __restrict__ hf, const float* __restrict__ Wf2,
                                                 const float* __restrict__ bf2, const float* __restrict__ x,
                                                 float* __restrict__ out) {
    int n = blockIdx.x * 256 + threadIdx.x;  // 16384 nodes
    const float* h = hf + (size_t)n * 256;
    float s0 = bf2[0], s1 = bf2[1], s2 = bf2[2];
    for (int k4 = 0; k4 < 64; ++k4) {
        float4 hv = *(const float4*)(h + k4 * 4);
        const float* w = Wf2 + k4 * 12;
        s0 = fmaf(hv.x, w[0], s0); s1 = fmaf(hv.x, w[1], s1); s2 = fmaf(hv.x, w[2], s2);
        s0 = fmaf(hv.y, w[3], s0); s1 = fmaf(hv.y, w[4], s1); s2 = fmaf(hv.y, w[5], s2);
        s0 = fmaf(hv.z, w[6], s0); s1 = fmaf(hv.z, w[7], s1); s2 = fmaf(hv.z, w[8], s2);
        s0 = fmaf(hv.w, w[9], s0); s1 = fmaf(hv.w, w[10], s1); s2 = fmaf(hv.w, w[11], s2);
    }
    out[n * 3 + 0] = x[n * 3 + 0] + s0;
    out[n * 3 + 1] = x[n * 3 + 1] + s1;
    out[n * 3 + 2] = x[n * 3 + 2] + s2;
}

extern "C" void kernel_launch(void* const* d_in, const int* in_sizes, int n_in,
                              void* d_out, int out_size, void* d_ws, size_t ws_size,
                              hipStream_t stream) {
    const float* x    = (const float*)d_in[0];
    const float* beta = (const float*)d_in[1];
    const float* ctxv = (const float*)d_in[2];
    const float* cond = (const float*)d_in[3];
    const float* W0   = (const float*)d_in[4];
    const float* b0   = (const float*)d_in[5];
    const float* ln_g = (const float*)d_in[6];
    const float* ln_b = (const float*)d_in[7];
    const float* W1   = (const float*)d_in[8];
    const float* b1   = (const float*)d_in[9];
    const float* W2   = (const float*)d_in[10];
    const float* b2   = (const float*)d_in[11];
    const float* W3   = (const float*)d_in[12];
    const float* b3   = (const float*)d_in[13];
    const float* Wf1  = (const float*)d_in[14];
    const float* bf1  = (const float*)d_in[15];
    const float* Wf2  = (const float*)d_in[16];
    const float* bf2  = (const float*)d_in[17];
    float* out = (float*)d_out;

    char* ws = (char*)d_ws;
    size_t off = 0;
    auto alloc = [&](size_t bytes) -> void* {
        void* p = ws + off;
        off += bytes;
        off = (off + 511) & ~(size_t)511;
        return p;
    };

    int*   idx   = (int*)alloc((size_t)M * 8 * 4);
    float* ctx   = (float*)alloc((size_t)BATCH * CTXW * 4);
    float* bias1 = (float*)alloc((size_t)BATCH * 128 * 4);
    float* bias2 = (float*)alloc((size_t)BATCH * 256 * 4);
    float* bias3 = (float*)alloc((size_t)BATCH * 512 * 4);
    float* W1p   = (float*)alloc((size_t)64 * 256 * 4);
    float* W2p   = (float*)alloc((size_t)128 * 512 * 4);
    float* W3p   = (float*)alloc((size_t)256 * 1024 * 4);
    float* R1    = (float*)alloc((size_t)M * 1024 * 4);  // feat0, later UV3
    float* R2    = (float*)alloc((size_t)M * 512 * 4);   // UV1, UV2, x3
    float* R3    = (float*)alloc((size_t)M * 256 * 4);   // x1, hf
    float* R4    = (float*)alloc((size_t)M * 256 * 4);   // x2

    float* feat0 = R1;
    float* UV1 = R2;  float* x1 = R3;
    float* UV2 = R2;  float* x2 = R4;
    float* UV3 = R1;  float* x3 = R2;
    float* hf  = R3;

    build_ctx<<<BATCH, 256, 0, stream>>>(beta, ctxv, cond, ctx);
    ctx_bias<<<(BATCH * 128 + 255) / 256, 256, 0, stream>>>(ctx, W1, b1, bias1, 128, 128);
    ctx_bias<<<(BATCH * 256 + 255) / 256, 256, 0, stream>>>(ctx, W2, b2, bias2, 256, 256);
    ctx_bias<<<(BATCH * 512 + 255) / 256, 256, 0, stream>>>(ctx, W3, b3, bias3, 512, 512);
    pack_w<<<(64 * 256 + 255) / 256, 256, 0, stream>>>(W1, W1p, 64, 128);
    pack_w<<<(128 * 512 + 255) / 256, 256, 0, stream>>>(W2, W2p, 128, 256);
    pack_w<<<(256 * 1024 + 255) / 256, 256, 0, stream>>>(W3, W3p, 256, 512);

    knn_kernel<<<dim3(NPTS / 32, BATCH), 256, 0, stream>>>(x, idx);
    init_ln<<<M * 64 / 256, 256, 0, stream>>>(x, W0, b0, ln_g, ln_b, feat0);

    gemm128x64<<<dim3(M / 128, 256 / 64), 256, 0, stream>>>(feat0, W1p, UV1, 256, 64, nullptr, 0);
    edge_max<<<M * (128 / 4) / 256, 256, 0, stream>>>(UV1, idx, bias1, x1, 128, 5);

    gemm128x64<<<dim3(M / 128, 512 / 64), 256, 0, stream>>>(x1, W2p, UV2, 512, 128, nullptr, 0);
    edge_max<<<M * (256 / 4) / 256, 256, 0, stream>>>(UV2, idx, bias2, x2, 256, 6);

    gemm128x64<<<dim3(M / 128, 1024 / 64), 256, 0, stream>>>(x2, W3p, UV3, 1024, 256, nullptr, 0);
    edge_max<<<M * (512 / 4) / 256, 256, 0, stream>>>(UV3, idx, bias3, x3, 512, 7);

    gemm128x64<<<dim3(M / 128, 256 / 64), 256, 0, stream>>>(x3, Wf1, hf, 256, 512, bf1, 1);

    final_out<<<M / 256, 256, 0, stream>>>(hf, Wf2, bf2, x, out);
}

// Round 3
// 357.520 us; speedup vs baseline: 2.4156x; 1.4840x over previous
//
#include <hip/hip_runtime.h>
#include <cfloat>

constexpr int BATCH = 8, NPTS = 2048;
constexpr int M = BATCH * NPTS;   // 16384 nodes
constexpr int CTXW = 515;

typedef __attribute__((ext_vector_type(8))) short bf16x8;
typedef __attribute__((ext_vector_type(4))) float f32x4;

__device__ __forceinline__ float lrelu(float v) { return v > 0.0f ? v : 0.2f * v; }
__device__ __forceinline__ float b2f(short u) {
    return __uint_as_float(((unsigned int)(unsigned short)u) << 16);
}
__device__ __forceinline__ short f2bf(float f) {
    unsigned int u = __float_as_uint(f);
    return (short)((u + 0x7FFF + ((u >> 16) & 1)) >> 16);
}

// ---------------- ctx vector ----------------
__global__ void build_ctx(const float* __restrict__ beta, const float* __restrict__ ctxv,
                          const float* __restrict__ cond, float* __restrict__ ctx) {
    int b = blockIdx.x;
    float be = beta[b];
    for (int i = threadIdx.x; i < CTXW; i += blockDim.x) {
        float v;
        if (i == 0) v = be;
        else if (i == 1) v = sinf(be);
        else if (i == 2) v = cosf(be);
        else if (i < 259) v = ctxv[b * 256 + (i - 3)];
        else v = cond[b * 256 + (i - 259)];
        ctx[b * CTXW + i] = v;
    }
}

// bias_ctx[b][f] = bvec[f] + sum_c ctx[b][c] * W[rowOff + c][f]; 4-way k-split
__global__ __launch_bounds__(256) void ctx_bias(const float* __restrict__ ctx, const float* __restrict__ W,
                                                const float* __restrict__ bvec, float* __restrict__ out,
                                                int rowOff, int F) {
    int b = blockIdx.y;
    int fl = threadIdx.x >> 2, ks = threadIdx.x & 3;
    int f = blockIdx.x * 64 + fl;
    const float* c = ctx + b * CTXW;
    const float* w = W + (size_t)rowOff * F + f;
    float s = 0.f;
    for (int i = ks; i < CTXW; i += 4) s = fmaf(c[i], w[(size_t)i * F], s);
    s += __shfl_xor(s, 1);
    s += __shfl_xor(s, 2);
    if (ks == 0) out[(size_t)b * F + f] = s + bvec[f];
}

// pack transposed bf16 cat-weight: out[(2F) x D], out[j][k] = j<F ? W[k][j] : W[D+k][j-F]
__global__ void pack_cat_t(const float* __restrict__ W, short* __restrict__ out, int D, int F) {
    int gid = blockIdx.x * blockDim.x + threadIdx.x;
    if (gid >= 2 * F * D) return;
    int j = gid / D, k = gid - j * D;
    float v = (j < F) ? W[(size_t)k * F + j] : W[(size_t)(D + k) * F + (j - F)];
    out[gid] = f2bf(v);
}

// Wf1 (512x256) -> transposed bf16 (256x512)
__global__ void pack_f1_t(const float* __restrict__ W, short* __restrict__ out) {
    int gid = blockIdx.x * blockDim.x + threadIdx.x;  // 131072
    int f = gid >> 9, k = gid & 511;
    out[gid] = f2bf(W[(size_t)k * 256 + f]);
}

// ---------------- kNN: 16 nodes x 16 chunks, fp64 (bit-identical to np ref) ----------------
__global__ __launch_bounds__(256) void knn_kernel(const float* __restrict__ x, int* __restrict__ idx) {
    __shared__ __align__(16) char pool[40960];
    float (*xs)[3] = (float(*)[3])pool;           // 24576 B
    double* sqs = (double*)(pool + 24576);        // 16384 B
    int b = blockIdx.y;
    const float* xb = x + (size_t)b * NPTS * 3;
    int tid = threadIdx.x;
    for (int i = tid; i < NPTS; i += 256) {
        float a0 = xb[i * 3], a1 = xb[i * 3 + 1], a2 = xb[i * 3 + 2];
        xs[i][0] = a0; xs[i][1] = a1; xs[i][2] = a2;
        sqs[i] = ((double)a0 * a0 + (double)a1 * a1) + (double)a2 * a2;
    }
    __syncthreads();

    int nl = tid & 15;            // node within block
    int chunk = tid >> 4;         // candidate chunk 0..15 (contiguous -> index-stable merge)
    int n = blockIdx.x * 16 + nl;
    float n0 = xs[n][0], n1 = xs[n][1], n2 = xs[n][2];
    double sqn = sqs[n];
    double best[8];
    int bi[8];
#pragma unroll
    for (int k = 0; k < 8; ++k) { best[k] = DBL_MAX; bi[k] = 0; }
    int mbase = chunk * 128;
    for (int i = 0; i < 128; ++i) {
        int m = mbase + i;
        double dot = ((double)n0 * xs[m][0] + (double)n1 * xs[m][1]) + (double)n2 * xs[m][2];
        double d = (sqn + sqs[m]) - 2.0 * dot;
        if (m != n && d < best[7]) {
            double cd = d; int ci = m;
#pragma unroll
            for (int j = 0; j < 8; ++j) {
                if (cd < best[j]) {
                    double td = best[j]; best[j] = cd; cd = td;
                    int ti = bi[j]; bi[j] = ci; ci = ti;
                }
            }
        }
    }
    __syncthreads();
    double* pd = (double*)pool;          // [128][16] = 16384 B
    int*    pi = (int*)(pool + 16384);   // [128][16] =  8192 B
#pragma unroll
    for (int k = 0; k < 8; ++k) {
        pd[(chunk * 8 + k) * 16 + nl] = best[k];
        pi[(chunk * 8 + k) * 16 + nl] = bi[k];
    }
    __syncthreads();
    if (tid < 16) {
        int node = tid;
        double fb[8]; int fi[8];
#pragma unroll
        for (int k = 0; k < 8; ++k) { fb[k] = DBL_MAX; fi[k] = 0; }
        for (int c = 0; c < 16; ++c) {
            for (int k = 0; k < 8; ++k) {
                double d = pd[(c * 8 + k) * 16 + node];
                if (d >= fb[7]) break;  // chunk lists ascending
                int ci = pi[(c * 8 + k) * 16 + node];
                double cd = d;
#pragma unroll
                for (int j = 0; j < 8; ++j) {
                    if (cd < fb[j]) {
                        double td = fb[j]; fb[j] = cd; cd = td;
                        int ti = fi[j]; fi[j] = ci; ci = ti;
                    }
                }
            }
        }
        int gn = b * NPTS + blockIdx.x * 16 + node;
#pragma unroll
        for (int k = 0; k < 8; ++k) idx[(size_t)gn * 8 + k] = b * NPTS + fi[k];
    }
}

// ---------------- init MLP + LayerNorm -> bf16 feat ----------------
__global__ __launch_bounds__(256) void init_ln(const float* __restrict__ x, const float* __restrict__ W0,
                                               const float* __restrict__ b0, const float* __restrict__ g,
                                               const float* __restrict__ be, short* __restrict__ feat) {
    int t = blockIdx.x * 256 + threadIdx.x;
    int node = t >> 6, c = t & 63;
    const float* xp = x + (size_t)node * 3;
    float h = fmaf(xp[0], W0[c], fmaf(xp[1], W0[64 + c], fmaf(xp[2], W0[128 + c], b0[c])));
    h = lrelu(h);
    float s = h;
#pragma unroll
    for (int o = 32; o > 0; o >>= 1) s += __shfl_xor(s, o);
    float mu = s * (1.0f / 64.0f);
    float tt = h - mu;
    float q = tt * tt;
#pragma unroll
    for (int o = 32; o > 0; o >>= 1) q += __shfl_xor(q, o);
    float var = q * (1.0f / 64.0f);
    feat[t] = f2bf(tt * rsqrtf(var + 1e-5f) * g[c] + be[c]);
}

// ---------------- bf16 MFMA GEMM: C(MxN) = A(MxK) @ Bt(NxK)^T, 128x128 tile, BK=64 ----------------
__global__ __launch_bounds__(256) void gemm_mfma(const short* __restrict__ A, const short* __restrict__ Bt,
                                                 short* __restrict__ C, int N, int K,
                                                 const float* __restrict__ bias, int fuse_lrelu) {
    __shared__ __align__(16) char Asw[128 * 128];  // 128 rows x 128B, XOR-swizzled
    __shared__ __align__(16) char Bsw[128 * 128];
    int tid = threadIdx.x;
    int lane = tid & 63, wid = tid >> 6;
    int wm = wid >> 1, wn = wid & 1;
    int mBase = blockIdx.x * 128, nBase = blockIdx.y * 128;
    int lo = lane & 15, hi = lane >> 4;

    f32x4 acc[4][4];
#pragma unroll
    for (int i = 0; i < 4; ++i)
#pragma unroll
        for (int j = 0; j < 4; ++j) acc[i][j] = (f32x4){0.f, 0.f, 0.f, 0.f};

    int sr = tid >> 3;   // 0..31
    int sc = tid & 7;    // 16B chunk in row

    for (int k0 = 0; k0 < K; k0 += 64) {
        bf16x8 av[4], bv[4];
#pragma unroll
        for (int i = 0; i < 4; ++i) {
            int row = i * 32 + sr;
            av[i] = *(const bf16x8*)(A + (size_t)(mBase + row) * K + k0 + sc * 8);
            bv[i] = *(const bf16x8*)(Bt + (size_t)(nBase + row) * K + k0 + sc * 8);
        }
        __syncthreads();
#pragma unroll
        for (int i = 0; i < 4; ++i) {
            int row = i * 32 + sr;
            int off = row * 128 + ((sc * 16) ^ ((row & 7) << 4));
            *(bf16x8*)(Asw + off) = av[i];
            *(bf16x8*)(Bsw + off) = bv[i];
        }
        __syncthreads();
#pragma unroll
        for (int kk = 0; kk < 2; ++kk) {
            bf16x8 af[4], bfr[4];
            int kb = kk * 64 + hi * 16;
#pragma unroll
            for (int q = 0; q < 4; ++q) {
                int rowA = wm * 64 + q * 16 + lo;
                af[q] = *(const bf16x8*)(Asw + rowA * 128 + (kb ^ ((rowA & 7) << 4)));
                int rowB = wn * 64 + q * 16 + lo;
                bfr[q] = *(const bf16x8*)(Bsw + rowB * 128 + (kb ^ ((rowB & 7) << 4)));
            }
#pragma unroll
            for (int fm = 0; fm < 4; ++fm)
#pragma unroll
                for (int fn = 0; fn < 4; ++fn)
                    acc[fm][fn] = __builtin_amdgcn_mfma_f32_16x16x32_bf16(af[fm], bfr[fn], acc[fm][fn], 0, 0, 0);
        }
    }

    // C/D layout (HW-verified): col = lane&15, row = (lane>>4)*4 + reg
#pragma unroll
    for (int fm = 0; fm < 4; ++fm) {
        int m0 = mBase + wm * 64 + fm * 16 + hi * 4;
#pragma unroll
        for (int fn = 0; fn < 4; ++fn) {
            int n = nBase + wn * 64 + fn * 16 + lo;
            float bb = bias ? bias[n] : 0.0f;
#pragma unroll
            for (int rr = 0; rr < 4; ++rr) {
                float v = acc[fm][fn][rr] + bb;
                if (fuse_lrelu) v = lrelu(v);
                C[(size_t)(m0 + rr) * N + n] = f2bf(v);
            }
        }
    }
}

// ---------------- edge aggregate: x[n] = lrelu(U[n] - V[n] + bias[b] + max_k V[idx_k]) ----------------
__global__ __launch_bounds__(256) void edge_max(const short* __restrict__ UV, const int* __restrict__ idx,
                                                const float* __restrict__ bias, short* __restrict__ out,
                                                int F, int lf /* log2(F/8) */) {
    int gid = blockIdx.x * 256 + threadIdx.x;
    int n = gid >> lf;
    int f = (gid & ((F >> 3) - 1)) << 3;
    int b = n >> 11;
    int F2 = F << 1;
    const short* base = UV + (size_t)n * F2;
    bf16x8 u8 = *(const bf16x8*)(base + f);
    bf16x8 v8 = *(const bf16x8*)(base + F + f);
    const int* ip = idx + (size_t)n * 8;
    float mx[8];
#pragma unroll
    for (int j = 0; j < 8; ++j) mx[j] = -FLT_MAX;
#pragma unroll
    for (int k = 0; k < 8; ++k) {
        bf16x8 w8 = *(const bf16x8*)(UV + (size_t)ip[k] * F2 + F + f);
#pragma unroll
        for (int j = 0; j < 8; ++j) mx[j] = fmaxf(mx[j], b2f(w8[j]));
    }
    const float* bp = bias + (size_t)b * F + f;
    bf16x8 z;
#pragma unroll
    for (int j = 0; j < 8; ++j)
        z[j] = f2bf(lrelu(b2f(u8[j]) - b2f(v8[j]) + bp[j] + mx[j]));
    *(bf16x8*)(out + (size_t)n * F + f) = z;
}

// ---------------- final: out = x + lrelu-free (hf bf16) @ Wf2 + bf2 ----------------
__global__ __launch_bounds__(256) void final_out(const short* __restrict__ hf, const float* __restrict__ Wf2,
                                                 const float* __restrict__ bf2, const float* __restrict__ x,
                                                 float* __restrict__ out) {
    int n = blockIdx.x * 256 + threadIdx.x;
    const short* h = hf + (size_t)n * 256;
    float s0 = bf2[0], s1 = bf2[1], s2 = bf2[2];
    for (int k8 = 0; k8 < 32; ++k8) {
        bf16x8 hv = *(const bf16x8*)(h + k8 * 8);
        const float* w = Wf2 + k8 * 24;
#pragma unroll
        for (int j = 0; j < 8; ++j) {
            float hh = b2f(hv[j]);
            s0 = fmaf(hh, w[j * 3 + 0], s0);
            s1 = fmaf(hh, w[j * 3 + 1], s1);
            s2 = fmaf(hh, w[j * 3 + 2], s2);
        }
    }
    out[n * 3 + 0] = x[n * 3 + 0] + s0;
    out[n * 3 + 1] = x[n * 3 + 1] + s1;
    out[n * 3 + 2] = x[n * 3 + 2] + s2;
}

extern "C" void kernel_launch(void* const* d_in, const int* in_sizes, int n_in,
                              void* d_out, int out_size, void* d_ws, size_t ws_size,
                              hipStream_t stream) {
    const float* x    = (const float*)d_in[0];
    const float* beta = (const float*)d_in[1];
    const float* ctxv = (const float*)d_in[2];
    const float* cond = (const float*)d_in[3];
    const float* W0   = (const float*)d_in[4];
    const float* b0   = (const float*)d_in[5];
    const float* ln_g = (const float*)d_in[6];
    const float* ln_b = (const float*)d_in[7];
    const float* W1   = (const float*)d_in[8];
    const float* b1   = (const float*)d_in[9];
    const float* W2   = (const float*)d_in[10];
    const float* b2   = (const float*)d_in[11];
    const float* W3   = (const float*)d_in[12];
    const float* b3   = (const float*)d_in[13];
    const float* Wf1  = (const float*)d_in[14];
    const float* bf1  = (const float*)d_in[15];
    const float* Wf2  = (const float*)d_in[16];
    const float* bf2  = (const float*)d_in[17];
    float* out = (float*)d_out;

    char* ws = (char*)d_ws;
    size_t off = 0;
    auto alloc = [&](size_t bytes) -> void* {
        void* p = ws + off;
        off += bytes;
        off = (off + 511) & ~(size_t)511;
        return p;
    };

    int*   idx   = (int*)alloc((size_t)M * 8 * 4);
    float* ctx   = (float*)alloc((size_t)BATCH * CTXW * 4);
    float* bias1 = (float*)alloc((size_t)BATCH * 128 * 4);
    float* bias2 = (float*)alloc((size_t)BATCH * 256 * 4);
    float* bias3 = (float*)alloc((size_t)BATCH * 512 * 4);
    short* W1p   = (short*)alloc((size_t)256 * 64 * 2);
    short* W2p   = (short*)alloc((size_t)512 * 128 * 2);
    short* W3p   = (short*)alloc((size_t)1024 * 256 * 2);
    short* Wf1p  = (short*)alloc((size_t)256 * 512 * 2);
    short* R1    = (short*)alloc((size_t)M * 1024 * 2);  // feat0, later UV3
    short* R2    = (short*)alloc((size_t)M * 512 * 2);   // UV1, UV2, x3
    short* R3    = (short*)alloc((size_t)M * 256 * 2);   // x1, hf
    short* R4    = (short*)alloc((size_t)M * 256 * 2);   // x2

    short* feat0 = R1;
    short* UV1 = R2;  short* x1 = R3;
    short* UV2 = R2;  short* x2 = R4;
    short* UV3 = R1;  short* x3 = R2;
    short* hf  = R3;

    build_ctx<<<BATCH, 256, 0, stream>>>(beta, ctxv, cond, ctx);
    ctx_bias<<<dim3(2, BATCH), 256, 0, stream>>>(ctx, W1, b1, bias1, 128, 128);
    ctx_bias<<<dim3(4, BATCH), 256, 0, stream>>>(ctx, W2, b2, bias2, 256, 256);
    ctx_bias<<<dim3(8, BATCH), 256, 0, stream>>>(ctx, W3, b3, bias3, 512, 512);
    pack_cat_t<<<(2 * 128 * 64 + 255) / 256, 256, 0, stream>>>(W1, W1p, 64, 128);
    pack_cat_t<<<(2 * 256 * 128 + 255) / 256, 256, 0, stream>>>(W2, W2p, 128, 256);
    pack_cat_t<<<(2 * 512 * 256 + 255) / 256, 256, 0, stream>>>(W3, W3p, 256, 512);
    pack_f1_t<<<(256 * 512 + 255) / 256, 256, 0, stream>>>(Wf1, Wf1p);

    knn_kernel<<<dim3(NPTS / 16, BATCH), 256, 0, stream>>>(x, idx);
    init_ln<<<M * 64 / 256, 256, 0, stream>>>(x, W0, b0, ln_g, ln_b, feat0);

    gemm_mfma<<<dim3(M / 128, 2), 256, 0, stream>>>(feat0, W1p, UV1, 256, 64, nullptr, 0);
    edge_max<<<M * 16 / 256, 256, 0, stream>>>(UV1, idx, bias1, x1, 128, 4);

    gemm_mfma<<<dim3(M / 128, 4), 256, 0, stream>>>(x1, W2p, UV2, 512, 128, nullptr, 0);
    edge_max<<<M * 32 / 256, 256, 0, stream>>>(UV2, idx, bias2, x2, 256, 5);

    gemm_mfma<<<dim3(M / 128, 8), 256, 0, stream>>>(x2, W3p, UV3, 1024, 256, nullptr, 0);
    edge_max<<<M * 64 / 256, 256, 0, stream>>>(UV3, idx, bias3, x3, 512, 6);

    gemm_mfma<<<dim3(M / 128, 2), 256, 0, stream>>>(x3, Wf1p, hf, 256, 512, bf1, 1);

    final_out<<<M / 256, 256, 0, stream>>>(hf, Wf2, bf2, x, out);
}